// Round 4
// baseline (644.603 us; speedup 1.0000x reference)
//
#include <hip/hip_runtime.h>
#include <hip/hip_bf16.h>
#include <math.h>

// Problem constants
#define T_TOKENS 8192      // B*S
#define DD 1024            // embed dim
#define HH 2752            // swiglu hidden (43*64)
#define EE 8               // experts
#define BM 128             // M tile (row segment alignment)
#define MT_MAX 136         // 2T/BM + E  (upper bound on total m-tiles)

typedef __attribute__((ext_vector_type(8))) short s16x8;
typedef __attribute__((ext_vector_type(4))) float f32x4;

__device__ __forceinline__ unsigned int f2bf1(float f) {
  unsigned int u = __float_as_uint(f);
  return (u + 0x7FFFu + ((u >> 16) & 1u)) >> 16;   // RNE fp32->bf16
}
__device__ __forceinline__ unsigned int f2bf2(float lo, float hi) {
  return f2bf1(lo) | (f2bf1(hi) << 16);
}

__device__ __forceinline__ void gload_lds16(const void* g, void* l) {
  __builtin_amdgcn_global_load_lds((const __attribute__((address_space(1))) void*)g,
                                   (__attribute__((address_space(3))) void*)l, 16, 0, 0);
}

// legacy B-tile swizzle (fallback kernels only)
__device__ __forceinline__ int bswz(int n) {
  return ((n >> 2) & 7) ^ ((n & 3) << 1);
}

// ---------------- router ----------------
__global__ void k_init(int* cursor) {
  if (threadIdx.x < EE) cursor[threadIdx.x] = 0;
}

__global__ void k_router(const float* __restrict__ x, const float* __restrict__ rw,
                         int* __restrict__ topi, float* __restrict__ topw) {
  int t = (blockIdx.x * blockDim.x + threadIdx.x) >> 6;
  int lane = threadIdx.x & 63;
  const float* xr = x + (size_t)t * DD;
  double acc[EE];
#pragma unroll
  for (int e = 0; e < EE; ++e) acc[e] = 0.0;
#pragma unroll
  for (int i = 0; i < DD / 64; ++i) {
    int d = lane + (i << 6);
    double xv = (double)xr[d];
    const float4* rp = (const float4*)(rw + (size_t)d * EE);
    float4 r0 = rp[0], r1 = rp[1];
    acc[0] += xv * (double)r0.x; acc[1] += xv * (double)r0.y;
    acc[2] += xv * (double)r0.z; acc[3] += xv * (double)r0.w;
    acc[4] += xv * (double)r1.x; acc[5] += xv * (double)r1.y;
    acc[6] += xv * (double)r1.z; acc[7] += xv * (double)r1.w;
  }
#pragma unroll
  for (int e = 0; e < EE; ++e) {
    double v = acc[e];
#pragma unroll
    for (int off = 32; off > 0; off >>= 1) v += __shfl_down(v, off, 64);
    acc[e] = v;
  }
  if (lane == 0) {
    int i1 = 0; double l1 = acc[0];
#pragma unroll
    for (int e = 1; e < EE; ++e) if (acc[e] > l1) { l1 = acc[e]; i1 = e; }
    int i2 = -1; double l2 = -1e300;
#pragma unroll
    for (int e = 0; e < EE; ++e) if (e != i1 && acc[e] > l2) { l2 = acc[e]; i2 = e; }
    double ee = exp(l2 - l1);
    float w1 = (float)(1.0 / (1.0 + ee));
    topi[2 * t] = i1; topi[2 * t + 1] = i2;
    topw[2 * t] = w1; topw[2 * t + 1] = 1.0f - w1;
  }
}

__global__ __launch_bounds__(256) void k_assign(int* __restrict__ topi,
                                                int* __restrict__ cursor) {
  __shared__ int hist[EE];
  __shared__ int base[EE];
  int t = blockIdx.x * 256 + threadIdx.x;
  if (threadIdx.x < EE) hist[threadIdx.x] = 0;
  __syncthreads();
  int e0 = topi[2 * t], e1 = topi[2 * t + 1];
  int r0 = atomicAdd(&hist[e0], 1);
  int r1 = atomicAdd(&hist[e1], 1);
  __syncthreads();
  if (threadIdx.x < EE) base[threadIdx.x] = atomicAdd(&cursor[threadIdx.x], hist[threadIdx.x]);
  __syncthreads();
  topi[2 * t]     = e0 | ((base[e0] + r0) << 3);
  topi[2 * t + 1] = e1 | ((base[e1] + r1) << 3);
}

__global__ void k_offsets(const int* __restrict__ cursor, int* __restrict__ cnt,
                          int* __restrict__ tpfx) {
  if (threadIdx.x == 0) {
    int acc = 0;
#pragma unroll
    for (int e = 0; e < EE; ++e) {
      cnt[e] = cursor[e];
      tpfx[e] = acc;
      acc += (cursor[e] + BM - 1) >> 7;
    }
    tpfx[EE] = acc;
  }
}

__global__ void k_copy(const float* __restrict__ x, const int* __restrict__ topi,
                       const float* __restrict__ topw, const int* __restrict__ tpfx,
                       int* __restrict__ tok, float* __restrict__ wgt,
                       unsigned short* __restrict__ Xg) {
  int t = (blockIdx.x * blockDim.x + threadIdx.x) >> 6;
  int lane = threadIdx.x & 63;
  int v0 = topi[2 * t], v1 = topi[2 * t + 1];
  int e0 = v0 & 7, e1 = v1 & 7;
  int r0 = (tpfx[e0] << 7) + (v0 >> 3);
  int r1 = (tpfx[e1] << 7) + (v1 >> 3);
  if (lane == 0) {
    tok[r0] = t; wgt[r0] = topw[2 * t];
    tok[r1] = t; wgt[r1] = topw[2 * t + 1];
  }
  const float4* xp = (const float4*)(x + (size_t)t * DD) + (lane << 2);
  float4 a = xp[0], b = xp[1], c = xp[2], d = xp[3];
  uint4 o0, o1;
  o0.x = f2bf2(a.x, a.y); o0.y = f2bf2(a.z, a.w);
  o0.z = f2bf2(b.x, b.y); o0.w = f2bf2(b.z, b.w);
  o1.x = f2bf2(c.x, c.y); o1.y = f2bf2(c.z, c.w);
  o1.z = f2bf2(d.x, d.y); o1.w = f2bf2(d.z, d.w);
  uint4* p0 = (uint4*)(Xg + (size_t)r0 * DD) + (lane << 1);
  p0[0] = o0; p0[1] = o1;
  uint4* p1 = (uint4*)(Xg + (size_t)r1 * DD) + (lane << 1);
  p1[0] = o0; p1[1] = o1;
}

__global__ void k_padzero(const int* __restrict__ cnt, const int* __restrict__ tpfx,
                          unsigned short* __restrict__ Xg) {
  int wid = (blockIdx.x * blockDim.x + threadIdx.x) >> 6;
  int lane = threadIdx.x & 63;
  int e = wid >> 7, i = wid & 127;
  int c = cnt[e];
  int padded = ((c + 127) >> 7) << 7;
  if (c + i < padded) {
    size_t row = ((size_t)tpfx[e] << 7) + (size_t)(c + i);
    uint4 z = make_uint4(0u, 0u, 0u, 0u);
    uint4* p = (uint4*)(Xg + row * DD) + (lane << 1);
    p[0] = z; p[1] = z;
  }
}

// ---------------- weight transpose+convert: fp32 [R][C] -> bf16 [C][R] ----------------
__global__ __launch_bounds__(256) void k_wtrans(const float* __restrict__ src,
                                                unsigned short* __restrict__ dst,
                                                int R, int C) {
  __shared__ unsigned int Lt[64 * 33];
  int ctn = C >> 6;
  int tiles = (R >> 6) * ctn;
  int bid = blockIdx.x;
  int e = bid / tiles, t = bid % tiles;
  int rt0 = (t / ctn) << 6, ct0 = (t % ctn) << 6;
  const float* s = src + (size_t)e * R * C;
  unsigned short* d = dst + (size_t)e * R * C;
  int tid = threadIdx.x;
  int rp = tid >> 3, cg = tid & 7;
  const float* p0 = s + (size_t)(rt0 + (rp << 1)) * C + ct0 + (cg << 3);
  float4 a0 = *(const float4*)p0;
  float4 a1 = *(const float4*)(p0 + 4);
  float4 b0 = *(const float4*)(p0 + C);
  float4 b1 = *(const float4*)(p0 + C + 4);
  float va[8] = {a0.x, a0.y, a0.z, a0.w, a1.x, a1.y, a1.z, a1.w};
  float vb[8] = {b0.x, b0.y, b0.z, b0.w, b1.x, b1.y, b1.z, b1.w};
#pragma unroll
  for (int j = 0; j < 8; ++j)
    Lt[((cg << 3) + j) * 33 + rp] = f2bf2(va[j], vb[j]);
  __syncthreads();
  int c = tid >> 2, q = tid & 3;
  unsigned int o[8];
#pragma unroll
  for (int i = 0; i < 8; ++i) o[i] = Lt[c * 33 + (q << 3) + i];
  unsigned short* pd = d + (size_t)(ct0 + c) * R + rt0 + (q << 4);
  *(uint4*)pd       = make_uint4(o[0], o[1], o[2], o[3]);
  *(uint4*)(pd + 8) = make_uint4(o[4], o[5], o[6], o[7]);
}

// ---------------- FC1 (dbuf 2-phase pipeline) ----------------
// tile 128(M) x 64(N per matrix) x 64(K); 4 waves (2x2); wave 64x32 per matrix
__global__ __launch_bounds__(256) void k_fc1t(
    const unsigned short* __restrict__ Xg, const unsigned short* __restrict__ wgT,
    const unsigned short* __restrict__ wuT, const int* __restrict__ tpfx,
    unsigned short* __restrict__ hbuf) {
  __shared__ unsigned short Al[2][BM * 64];   // 32 KB
  __shared__ unsigned short Bgl[2][64 * 64];  // 16 KB
  __shared__ unsigned short Bul[2][64 * 64];  // 16 KB
  int flat = blockIdx.x + blockIdx.y * MT_MAX;      // grid (136,43), 5848 = 8*731
  int swz = (flat & 7) * 731 + (flat >> 3);         // XCD-chunked, m-fastest
  int mt = swz % MT_MAX;
  int nb = swz / MT_MAX;
  if (mt >= tpfx[EE]) return;
  int e = 0;
  while (mt >= tpfx[e + 1]) ++e;
  int n0 = nb << 6;
  size_t row0 = (size_t)mt << 7;
  const unsigned short* wge = wgT + (size_t)e * DD * HH;
  const unsigned short* wue = wuT + (size_t)e * DD * HH;
  int tid = threadIdx.x, wv = tid >> 6, lane = tid & 63;
  int wm = wv >> 1, wn = wv & 1;

  f32x4 zf = {0.f, 0.f, 0.f, 0.f};
  f32x4 ag[4][2], au[4][2];
#pragma unroll
  for (int i = 0; i < 4; ++i)
#pragma unroll
    for (int j = 0; j < 2; ++j) { ag[i][j] = zf; au[i][j] = zf; }

  // per-wave staging addresses (lane-invariant parts hoisted)
  auto stage = [&](int b, int kt) {
    int k0 = kt << 6;
#pragma unroll
    for (int i = 0; i < 4; ++i) {
      int g = (wv << 2) + i;
      int p = (g << 6) + lane;
      int r = p >> 3, c = (p & 7) ^ (r & 7);
      gload_lds16(Xg + (row0 + r) * DD + (size_t)(k0 + (c << 3)),
                  &Al[b][(size_t)g << 9]);
    }
#pragma unroll
    for (int i = 0; i < 2; ++i) {
      int g = (wv << 1) + i;
      int p = (g << 6) + lane;
      int n = p >> 3, c = (p & 7) ^ (n & 7);
      gload_lds16(wge + (size_t)(n0 + n) * DD + (size_t)(k0 + (c << 3)),
                  &Bgl[b][(size_t)g << 9]);
      gload_lds16(wue + (size_t)(n0 + n) * DD + (size_t)(k0 + (c << 3)),
                  &Bul[b][(size_t)g << 9]);
    }
  };

  stage(0, 0);
  __syncthreads();          // vmcnt(0) drain + barrier: buf0 ready
  int cur = 0;
  for (int kt = 0; kt < DD / 64; ++kt) {
    if (kt + 1 < DD / 64) stage(cur ^ 1, kt + 1);   // overlapped with MFMA below
#pragma unroll
    for (int ks = 0; ks < 2; ++ks) {
      int cch = (ks << 2) + (lane >> 4);
      s16x8 af[4];
#pragma unroll
      for (int fm = 0; fm < 4; ++fm) {
        int r = (wm << 6) + (fm << 4) + (lane & 15);
        af[fm] = *(const s16x8*)(&Al[cur][0] + (r << 6) + ((cch ^ (r & 7)) << 3));
      }
      s16x8 bg[2], bu[2];
#pragma unroll
      for (int fn = 0; fn < 2; ++fn) {
        int n = (wn << 5) + (fn << 4) + (lane & 15);
        int o = (n << 6) + ((cch ^ (n & 7)) << 3);
        bg[fn] = *(const s16x8*)(&Bgl[cur][0] + o);
        bu[fn] = *(const s16x8*)(&Bul[cur][0] + o);
      }
#pragma unroll
      for (int fm = 0; fm < 4; ++fm)
#pragma unroll
        for (int fn = 0; fn < 2; ++fn) {
          ag[fm][fn] = __builtin_amdgcn_mfma_f32_16x16x32_bf16(af[fm], bg[fn], ag[fm][fn], 0, 0, 0);
          au[fm][fn] = __builtin_amdgcn_mfma_f32_16x16x32_bf16(af[fm], bu[fn], au[fm][fn], 0, 0, 0);
        }
    }
    __syncthreads();        // single barrier/K-step: drains next-tile loads too
    cur ^= 1;
  }
#pragma unroll
  for (int fm = 0; fm < 4; ++fm)
#pragma unroll
    for (int fn = 0; fn < 2; ++fn)
#pragma unroll
      for (int j = 0; j < 4; ++j) {
        float gv = ag[fm][fn][j];
        float uv = au[fm][fn][j];
        float hv = gv / (1.f + __expf(-gv)) * uv;
        int r = (wm << 6) + (fm << 4) + ((lane >> 4) << 2) + j;
        int cc = (wn << 5) + (fn << 4) + (lane & 15);
        hbuf[(row0 + r) * HH + (size_t)(n0 + cc)] = (unsigned short)f2bf1(hv);
      }
}

// ---------------- FC2 (dbuf 2-phase pipeline) ----------------
// tile 128(M) x 128(N) x 64(K); 4 waves (2x2); wave 64x64
__global__ __launch_bounds__(256) void k_fc2t(
    const unsigned short* __restrict__ hbuf, const unsigned short* __restrict__ wdT,
    const int* __restrict__ cnt, const int* __restrict__ tpfx,
    const int* __restrict__ tok, const float* __restrict__ wgt,
    float* __restrict__ out) {
  __shared__ unsigned short Al[2][BM * 64];    // 32 KB
  __shared__ unsigned short Bl[2][128 * 64];   // 32 KB
  int flat = blockIdx.x + blockIdx.y * MT_MAX;      // grid (136,8), 1088 = 8*136
  int swz = (flat & 7) * MT_MAX + (flat >> 3);
  int mt = swz % MT_MAX;
  int nb = swz / MT_MAX;
  if (mt >= tpfx[EE]) return;
  int e = 0;
  while (mt >= tpfx[e + 1]) ++e;
  int n0 = nb << 7;
  size_t row0 = (size_t)mt << 7;
  int mrem = cnt[e] - ((mt - tpfx[e]) << 7);
  if (mrem > 128) mrem = 128;
  const unsigned short* wde = wdT + (size_t)e * DD * HH;  // [1024][2752]
  int tid = threadIdx.x, wv = tid >> 6, lane = tid & 63;
  int wm = wv >> 1, wn = wv & 1;

  f32x4 zf = {0.f, 0.f, 0.f, 0.f};
  f32x4 acc[4][4];
#pragma unroll
  for (int i = 0; i < 4; ++i)
#pragma unroll
    for (int j = 0; j < 4; ++j) acc[i][j] = zf;

  auto stage = [&](int b, int kt) {
    int k0 = kt << 6;
#pragma unroll
    for (int i = 0; i < 4; ++i) {
      int g = (wv << 2) + i;
      int p = (g << 6) + lane;
      int r = p >> 3, c = (p & 7) ^ (r & 7);
      gload_lds16(hbuf + (row0 + r) * HH + (size_t)(k0 + (c << 3)),
                  &Al[b][(size_t)g << 9]);
      gload_lds16(wde + (size_t)(n0 + r) * HH + (size_t)(k0 + (c << 3)),
                  &Bl[b][(size_t)g << 9]);
    }
  };

  stage(0, 0);
  __syncthreads();
  int cur = 0;
  for (int kt = 0; kt < HH / 64; ++kt) {
    if (kt + 1 < HH / 64) stage(cur ^ 1, kt + 1);
#pragma unroll
    for (int ks = 0; ks < 2; ++ks) {
      int cch = (ks << 2) + (lane >> 4);
      s16x8 af[4], bf[4];
#pragma unroll
      for (int fm = 0; fm < 4; ++fm) {
        int r = (wm << 6) + (fm << 4) + (lane & 15);
        af[fm] = *(const s16x8*)(&Al[cur][0] + (r << 6) + ((cch ^ (r & 7)) << 3));
      }
#pragma unroll
      for (int fn = 0; fn < 4; ++fn) {
        int n = (wn << 6) + (fn << 4) + (lane & 15);
        bf[fn] = *(const s16x8*)(&Bl[cur][0] + (n << 6) + ((cch ^ (n & 7)) << 3));
      }
#pragma unroll
      for (int fm = 0; fm < 4; ++fm)
#pragma unroll
        for (int fn = 0; fn < 4; ++fn)
          acc[fm][fn] = __builtin_amdgcn_mfma_f32_16x16x32_bf16(af[fm], bf[fn], acc[fm][fn], 0, 0, 0);
    }
    __syncthreads();
    cur ^= 1;
  }
#pragma unroll
  for (int fm = 0; fm < 4; ++fm)
#pragma unroll
    for (int j = 0; j < 4; ++j) {
      int r = (wm << 6) + (fm << 4) + ((lane >> 4) << 2) + j;
      if (r < mrem) {
        int tk = tok[row0 + r];
        float cw = wgt[row0 + r];
        float* ob = out + (size_t)tk * DD + (size_t)(n0 + (wn << 6) + (lane & 15));
#pragma unroll
        for (int fn = 0; fn < 4; ++fn)
          atomicAdd(ob + (fn << 4), acc[fm][fn][j] * cw);
      }
    }
}

// ================= fallback (round-2) kernels: in-loop fp32->bf16 convert =================
__global__ __launch_bounds__(256) void k_fc1_cv(
    const unsigned short* __restrict__ Xg, const float* __restrict__ wg,
    const float* __restrict__ wu, const int* __restrict__ tpfx,
    unsigned short* __restrict__ hbuf) {
  __shared__ unsigned short Al[BM * 64];
  __shared__ unsigned short Bgl[64 * 64];
  __shared__ unsigned short Bul[64 * 64];
  int mt = blockIdx.x;
  if (mt >= tpfx[EE]) return;
  int e = 0;
  while (mt >= tpfx[e + 1]) ++e;
  int n0 = blockIdx.y << 6;
  size_t row0 = (size_t)mt << 7;
  const float* wge = wg + (size_t)e * DD * HH;
  const float* wue = wu + (size_t)e * DD * HH;
  int tid = threadIdx.x, wv = tid >> 6, lane = tid & 63;
  int wm = wv >> 1, wn = wv & 1;
  f32x4 zf = {0.f, 0.f, 0.f, 0.f};
  f32x4 ag[4][2], au[4][2];
#pragma unroll
  for (int i = 0; i < 4; ++i)
#pragma unroll
    for (int j = 0; j < 2; ++j) { ag[i][j] = zf; au[i][j] = zf; }
  for (int kt = 0; kt < DD / 64; ++kt) {
    int k0 = kt << 6;
#pragma unroll
    for (int i = 0; i < 4; ++i) {
      int g = (wv << 2) + i;
      int p = (g << 6) + lane;
      int r = p >> 3, c = (p & 7) ^ (r & 7);
      gload_lds16(Xg + (row0 + r) * DD + (size_t)(k0 + (c << 3)), Al + ((size_t)g << 9));
    }
#pragma unroll
    for (int a2 = 0; a2 < 2; ++a2) {
      int idx = tid + (a2 << 8);
      int kk = (idx >> 4) << 1;
      int nn = (idx & 15) << 2;
      const float* pg = wge + (size_t)(k0 + kk) * HH + (n0 + nn);
      const float* pu = wue + (size_t)(k0 + kk) * HH + (n0 + nn);
      float4 g0 = *(const float4*)pg;
      float4 g1 = *(const float4*)(pg + HH);
      float4 u0 = *(const float4*)pu;
      float4 u1 = *(const float4*)(pu + HH);
      const float* g0f = (const float*)&g0; const float* g1f = (const float*)&g1;
      const float* u0f = (const float*)&u0; const float* u1f = (const float*)&u1;
      int kb = kk << 1, ch = kb >> 4, inb = kb & 15;
#pragma unroll
      for (int j = 0; j < 4; ++j) {
        int n = nn + j;
        int off = (n << 7) + ((ch ^ bswz(n)) << 4) + inb;
        *(unsigned int*)((char*)Bgl + off) = f2bf2(g0f[j], g1f[j]);
        *(unsigned int*)((char*)Bul + off) = f2bf2(u0f[j], u1f[j]);
      }
    }
    __syncthreads();
#pragma unroll
    for (int ks = 0; ks < 2; ++ks) {
      int cch = (ks << 2) + (lane >> 4);
      s16x8 af[4];
#pragma unroll
      for (int fm = 0; fm < 4; ++fm) {
        int r = (wm << 6) + (fm << 4) + (lane & 15);
        af[fm] = *(const s16x8*)(Al + (r << 6) + ((cch ^ (r & 7)) << 3));
      }
      s16x8 bg[2], bu[2];
#pragma unroll
      for (int fn = 0; fn < 2; ++fn) {
        int n = (wn << 5) + (fn << 4) + (lane & 15);
        int o = (n << 6) + ((cch ^ bswz(n)) << 3);
        bg[fn] = *(const s16x8*)(Bgl + o);
        bu[fn] = *(const s16x8*)(Bul + o);
      }
#pragma unroll
      for (int fm = 0; fm < 4; ++fm)
#pragma unroll
        for (int fn = 0; fn < 2; ++fn) {
          ag[fm][fn] = __builtin_amdgcn_mfma_f32_16x16x32_bf16(af[fm], bg[fn], ag[fm][fn], 0, 0, 0);
          au[fm][fn] = __builtin_amdgcn_mfma_f32_16x16x32_bf16(af[fm], bu[fn], au[fm][fn], 0, 0, 0);
        }
    }
    __syncthreads();
  }
#pragma unroll
  for (int fm = 0; fm < 4; ++fm)
#pragma unroll
    for (int fn = 0; fn < 2; ++fn)
#pragma unroll
      for (int j = 0; j < 4; ++j) {
        float gv = ag[fm][fn][j];
        float uv = au[fm][fn][j];
        float hv = gv / (1.f + __expf(-gv)) * uv;
        int r = (wm << 6) + (fm << 4) + ((lane >> 4) << 2) + j;
        int cc = (wn << 5) + (fn << 4) + (lane & 15);
        hbuf[(row0 + r) * HH + (size_t)(n0 + cc)] = (unsigned short)f2bf1(hv);
      }
}

__global__ __launch_bounds__(256) void k_fc2_cv(
    const unsigned short* __restrict__ hbuf, const float* __restrict__ wd,
    const int* __restrict__ cnt, const int* __restrict__ tpfx,
    const int* __restrict__ tok, const float* __restrict__ wgt,
    float* __restrict__ out) {
  __shared__ unsigned short Al[BM * 64];
  __shared__ unsigned short Bl[128 * 64];
  int mt = blockIdx.x;
  if (mt >= tpfx[EE]) return;
  int e = 0;
  while (mt >= tpfx[e + 1]) ++e;
  int n0 = blockIdx.y << 7;
  size_t row0 = (size_t)mt << 7;
  int mrem = cnt[e] - ((mt - tpfx[e]) << 7);
  if (mrem > 128) mrem = 128;
  const float* wde = wd + (size_t)e * HH * DD;
  int tid = threadIdx.x, wv = tid >> 6, lane = tid & 63;
  int wm = wv >> 1, wn = wv & 1;
  f32x4 zf = {0.f, 0.f, 0.f, 0.f};
  f32x4 acc[4][4];
#pragma unroll
  for (int i = 0; i < 4; ++i)
#pragma unroll
    for (int j = 0; j < 4; ++j) acc[i][j] = zf;
  for (int kt = 0; kt < HH / 64; ++kt) {
    int k0 = kt << 6;
#pragma unroll
    for (int i = 0; i < 4; ++i) {
      int g = (wv << 2) + i;
      int p = (g << 6) + lane;
      int r = p >> 3, c = (p & 7) ^ (r & 7);
      gload_lds16(hbuf + (row0 + r) * HH + (size_t)(k0 + (c << 3)), Al + ((size_t)g << 9));
    }
#pragma unroll
    for (int a2 = 0; a2 < 4; ++a2) {
      int idx = tid + (a2 << 8);
      int kk = (idx >> 5) << 1;
      int nn = (idx & 31) << 2;
      const float* pb = wde + (size_t)(k0 + kk) * DD + (n0 + nn);
      float4 b0 = *(const float4*)pb;
      float4 b1 = *(const float4*)(pb + DD);
      const float* b0f = (const float*)&b0;
      const float* b1f = (const float*)&b1;
      int kb = kk << 1, ch = kb >> 4, inb = kb & 15;
#pragma unroll
      for (int j = 0; j < 4; ++j) {
        int n = nn + j;
        int off = (n << 7) + ((ch ^ bswz(n)) << 4) + inb;
        *(unsigned int*)((char*)Bl + off) = f2bf2(b0f[j], b1f[j]);
      }
    }
    __syncthreads();
#pragma unroll
    for (int ks = 0; ks < 2; ++ks) {
      int cch = (ks << 2) + (lane >> 4);
      s16x8 af[4], bf[4];
#pragma unroll
      for (int fm = 0; fm < 4; ++fm) {
        int r = (wm << 6) + (fm << 4) + (lane & 15);
        af[fm] = *(const s16x8*)(Al + (r << 6) + ((cch ^ (r & 7)) << 3));
      }
#pragma unroll
      for (int fn = 0; fn < 4; ++fn) {
        int n = (wn << 6) + (fn << 4) + (lane & 15);
        bf[fn] = *(const s16x8*)(Bl + (n << 6) + ((cch ^ bswz(n)) << 3));
      }
#pragma unroll
      for (int fm = 0; fm < 4; ++fm)
#pragma unroll
        for (int fn = 0; fn < 4; ++fn)
          acc[fm][fn] = __builtin_amdgcn_mfma_f32_16x16x32_bf16(af[fm], bf[fn], acc[fm][fn], 0, 0, 0);
    }
    __syncthreads();
  }
#pragma unroll
  for (int fm = 0; fm < 4; ++fm)
#pragma unroll
    for (int j = 0; j < 4; ++j) {
      int r = (wm << 6) + (fm << 4) + ((lane >> 4) << 2) + j;
      if (r < mrem) {
        int tk = tok[row0 + r];
        float cw = wgt[row0 + r];
        float* ob = out + (size_t)tk * DD + (size_t)(n0 + (wn << 6) + (lane & 15));
#pragma unroll
        for (int fn = 0; fn < 4; ++fn)
          atomicAdd(ob + (fn << 4), acc[fm][fn][j] * cw);
      }
    }
}

extern "C" void kernel_launch(void* const* d_in, const int* in_sizes, int n_in,
                              void* d_out, int out_size, void* d_ws, size_t ws_size,
                              hipStream_t stream) {
  const float* x  = (const float*)d_in[0];
  const float* rw = (const float*)d_in[1];
  const float* wg = (const float*)d_in[2];
  const float* wu = (const float*)d_in[3];
  const float* wd = (const float*)d_in[4];
  float* out = (float*)d_out;

  // workspace layout
  char* w = (char*)d_ws;
  int* cnt    = (int*)(w + 0);
  int* cursor = (int*)(w + 32);
  int* tpfx   = (int*)(w + 64);
  int* topi   = (int*)(w + 256);
  float* topw = (float*)(w + 65792);
  int* tok    = (int*)(w + 131328);
  float* wgt  = (float*)(w + 200960);
  unsigned short* Xg  = (unsigned short*)(w + 270592);       // 35,651,584 B
  unsigned short* hb  = (unsigned short*)(w + 35922176ULL);  // 95,813,632 B
  unsigned short* wgT = (unsigned short*)(w + 131735808ULL); // 45,088,768 B
  unsigned short* wuT = (unsigned short*)(w + 176824576ULL); // 45,088,768 B
  unsigned short* wdT = wgT;  // reuses wgT slot AFTER fc1
  const size_t NEED = 221913344ULL;

  hipMemsetAsync(d_out, 0, (size_t)T_TOKENS * DD * sizeof(float), stream);
  k_init<<<1, 64, 0, stream>>>(cursor);
  k_router<<<T_TOKENS / 4, 256, 0, stream>>>(x, rw, topi, topw);
  k_assign<<<T_TOKENS / 256, 256, 0, stream>>>(topi, cursor);
  k_offsets<<<1, 64, 0, stream>>>(cursor, cnt, tpfx);
  k_copy<<<T_TOKENS / 4, 256, 0, stream>>>(x, topi, topw, tpfx, tok, wgt, Xg);
  k_padzero<<<256, 256, 0, stream>>>(cnt, tpfx, Xg);

  if (ws_size >= NEED) {
    k_wtrans<<<EE * 16 * 43, 256, 0, stream>>>(wg, wgT, DD, HH);
    k_wtrans<<<EE * 16 * 43, 256, 0, stream>>>(wu, wuT, DD, HH);
    k_fc1t<<<dim3(MT_MAX, HH / 64), 256, 0, stream>>>(Xg, wgT, wuT, tpfx, hb);
    k_wtrans<<<EE * 43 * 16, 256, 0, stream>>>(wd, wdT, HH, DD);  // over wgT slot
    k_fc2t<<<dim3(MT_MAX, DD / 128), 256, 0, stream>>>(hb, wdT, cnt, tpfx, tok, wgt, out);
  } else {
    k_fc1_cv<<<dim3(MT_MAX, HH / 64), 256, 0, stream>>>(Xg, wg, wu, tpfx, hb);
    k_fc2_cv<<<dim3(MT_MAX, DD / 128), 256, 0, stream>>>(hb, wd, cnt, tpfx, tok, wgt, out);
  }
}

// Round 5
// 633.496 us; speedup vs baseline: 1.0175x; 1.0175x over previous
//
#include <hip/hip_runtime.h>
#include <hip/hip_bf16.h>
#include <math.h>

// Problem constants
#define T_TOKENS 8192      // B*S
#define DD 1024            // embed dim
#define HH 2752            // swiglu hidden (43*64)
#define EE 8               // experts
#define BM 128             // M tile (row segment alignment)
#define MT_MAX 136         // 2T/BM + E  (upper bound on total m-tiles)

typedef __attribute__((ext_vector_type(8))) short s16x8;
typedef __attribute__((ext_vector_type(4))) float f32x4;

__device__ __forceinline__ unsigned int f2bf1(float f) {
  unsigned int u = __float_as_uint(f);
  return (u + 0x7FFFu + ((u >> 16) & 1u)) >> 16;   // RNE fp32->bf16
}
__device__ __forceinline__ unsigned int f2bf2(float lo, float hi) {
  return f2bf1(lo) | (f2bf1(hi) << 16);
}

__device__ __forceinline__ void gload_lds16(const void* g, void* l) {
  __builtin_amdgcn_global_load_lds((const __attribute__((address_space(1))) void*)g,
                                   (__attribute__((address_space(3))) void*)l, 16, 0, 0);
}

// legacy B-tile swizzle (fallback kernels only)
__device__ __forceinline__ int bswz(int n) {
  return ((n >> 2) & 7) ^ ((n & 3) << 1);
}

// ---------------- router ----------------
__global__ void k_init(int* cursor) {
  if (threadIdx.x < EE) cursor[threadIdx.x] = 0;
}

__global__ void k_router(const float* __restrict__ x, const float* __restrict__ rw,
                         int* __restrict__ topi, float* __restrict__ topw) {
  int t = (blockIdx.x * blockDim.x + threadIdx.x) >> 6;
  int lane = threadIdx.x & 63;
  const float* xr = x + (size_t)t * DD;
  double acc[EE];
#pragma unroll
  for (int e = 0; e < EE; ++e) acc[e] = 0.0;
#pragma unroll
  for (int i = 0; i < DD / 64; ++i) {
    int d = lane + (i << 6);
    double xv = (double)xr[d];
    const float4* rp = (const float4*)(rw + (size_t)d * EE);
    float4 r0 = rp[0], r1 = rp[1];
    acc[0] += xv * (double)r0.x; acc[1] += xv * (double)r0.y;
    acc[2] += xv * (double)r0.z; acc[3] += xv * (double)r0.w;
    acc[4] += xv * (double)r1.x; acc[5] += xv * (double)r1.y;
    acc[6] += xv * (double)r1.z; acc[7] += xv * (double)r1.w;
  }
#pragma unroll
  for (int e = 0; e < EE; ++e) {
    double v = acc[e];
#pragma unroll
    for (int off = 32; off > 0; off >>= 1) v += __shfl_down(v, off, 64);
    acc[e] = v;
  }
  if (lane == 0) {
    int i1 = 0; double l1 = acc[0];
#pragma unroll
    for (int e = 1; e < EE; ++e) if (acc[e] > l1) { l1 = acc[e]; i1 = e; }
    int i2 = -1; double l2 = -1e300;
#pragma unroll
    for (int e = 0; e < EE; ++e) if (e != i1 && acc[e] > l2) { l2 = acc[e]; i2 = e; }
    double ee = exp(l2 - l1);
    float w1 = (float)(1.0 / (1.0 + ee));
    topi[2 * t] = i1; topi[2 * t + 1] = i2;
    topw[2 * t] = w1; topw[2 * t + 1] = 1.0f - w1;
  }
}

__global__ __launch_bounds__(256) void k_assign(int* __restrict__ topi,
                                                int* __restrict__ cursor) {
  __shared__ int hist[EE];
  __shared__ int base[EE];
  int t = blockIdx.x * 256 + threadIdx.x;
  if (threadIdx.x < EE) hist[threadIdx.x] = 0;
  __syncthreads();
  int e0 = topi[2 * t], e1 = topi[2 * t + 1];
  int r0 = atomicAdd(&hist[e0], 1);
  int r1 = atomicAdd(&hist[e1], 1);
  __syncthreads();
  if (threadIdx.x < EE) base[threadIdx.x] = atomicAdd(&cursor[threadIdx.x], hist[threadIdx.x]);
  __syncthreads();
  topi[2 * t]     = e0 | ((base[e0] + r0) << 3);
  topi[2 * t + 1] = e1 | ((base[e1] + r1) << 3);
}

__global__ void k_offsets(const int* __restrict__ cursor, int* __restrict__ cnt,
                          int* __restrict__ tpfx) {
  if (threadIdx.x == 0) {
    int acc = 0;
#pragma unroll
    for (int e = 0; e < EE; ++e) {
      cnt[e] = cursor[e];
      tpfx[e] = acc;
      acc += (cursor[e] + BM - 1) >> 7;
    }
    tpfx[EE] = acc;
  }
}

__global__ void k_copy(const float* __restrict__ x, const int* __restrict__ topi,
                       const float* __restrict__ topw, const int* __restrict__ tpfx,
                       int* __restrict__ tok, float* __restrict__ wgt,
                       unsigned short* __restrict__ Xg) {
  int t = (blockIdx.x * blockDim.x + threadIdx.x) >> 6;
  int lane = threadIdx.x & 63;
  int v0 = topi[2 * t], v1 = topi[2 * t + 1];
  int e0 = v0 & 7, e1 = v1 & 7;
  int r0 = (tpfx[e0] << 7) + (v0 >> 3);
  int r1 = (tpfx[e1] << 7) + (v1 >> 3);
  if (lane == 0) {
    tok[r0] = t; wgt[r0] = topw[2 * t];
    tok[r1] = t; wgt[r1] = topw[2 * t + 1];
  }
  const float4* xp = (const float4*)(x + (size_t)t * DD) + (lane << 2);
  float4 a = xp[0], b = xp[1], c = xp[2], d = xp[3];
  uint4 o0, o1;
  o0.x = f2bf2(a.x, a.y); o0.y = f2bf2(a.z, a.w);
  o0.z = f2bf2(b.x, b.y); o0.w = f2bf2(b.z, b.w);
  o1.x = f2bf2(c.x, c.y); o1.y = f2bf2(c.z, c.w);
  o1.z = f2bf2(d.x, d.y); o1.w = f2bf2(d.z, d.w);
  uint4* p0 = (uint4*)(Xg + (size_t)r0 * DD) + (lane << 1);
  p0[0] = o0; p0[1] = o1;
  uint4* p1 = (uint4*)(Xg + (size_t)r1 * DD) + (lane << 1);
  p1[0] = o0; p1[1] = o1;
}

__global__ void k_padzero(const int* __restrict__ cnt, const int* __restrict__ tpfx,
                          unsigned short* __restrict__ Xg) {
  int wid = (blockIdx.x * blockDim.x + threadIdx.x) >> 6;
  int lane = threadIdx.x & 63;
  int e = wid >> 7, i = wid & 127;
  int c = cnt[e];
  int padded = ((c + 127) >> 7) << 7;
  if (c + i < padded) {
    size_t row = ((size_t)tpfx[e] << 7) + (size_t)(c + i);
    uint4 z = make_uint4(0u, 0u, 0u, 0u);
    uint4* p = (uint4*)(Xg + row * DD) + (lane << 1);
    p[0] = z; p[1] = z;
  }
}

// ---------------- weight transpose+convert: fp32 [R][C] -> bf16 [C][R] ----------------
__global__ __launch_bounds__(256) void k_wtrans(const float* __restrict__ src,
                                                unsigned short* __restrict__ dst,
                                                int R, int C) {
  __shared__ unsigned int Lt[64 * 33];
  int ctn = C >> 6;
  int tiles = (R >> 6) * ctn;
  int bid = blockIdx.x;
  int e = bid / tiles, t = bid % tiles;
  int rt0 = (t / ctn) << 6, ct0 = (t % ctn) << 6;
  const float* s = src + (size_t)e * R * C;
  unsigned short* d = dst + (size_t)e * R * C;
  int tid = threadIdx.x;
  int rp = tid >> 3, cg = tid & 7;
  const float* p0 = s + (size_t)(rt0 + (rp << 1)) * C + ct0 + (cg << 3);
  float4 a0 = *(const float4*)p0;
  float4 a1 = *(const float4*)(p0 + 4);
  float4 b0 = *(const float4*)(p0 + C);
  float4 b1 = *(const float4*)(p0 + C + 4);
  float va[8] = {a0.x, a0.y, a0.z, a0.w, a1.x, a1.y, a1.z, a1.w};
  float vb[8] = {b0.x, b0.y, b0.z, b0.w, b1.x, b1.y, b1.z, b1.w};
#pragma unroll
  for (int j = 0; j < 8; ++j)
    Lt[((cg << 3) + j) * 33 + rp] = f2bf2(va[j], vb[j]);
  __syncthreads();
  int c = tid >> 2, q = tid & 3;
  unsigned int o[8];
#pragma unroll
  for (int i = 0; i < 8; ++i) o[i] = Lt[c * 33 + (q << 3) + i];
  unsigned short* pd = d + (size_t)(ct0 + c) * R + rt0 + (q << 4);
  *(uint4*)pd       = make_uint4(o[0], o[1], o[2], o[3]);
  *(uint4*)(pd + 8) = make_uint4(o[4], o[5], o[6], o[7]);
}

// ---------------- FC1: depth-2 pipeline, counted vmcnt(8), raw barriers ----------------
// tile 128(M) x 64(N per matrix) x 64(K); 4 waves (2x2); wave 64x32 per matrix
__global__ __launch_bounds__(256) void k_fc1t(
    const unsigned short* __restrict__ Xg, const unsigned short* __restrict__ wgT,
    const unsigned short* __restrict__ wuT, const int* __restrict__ tpfx,
    unsigned short* __restrict__ hbuf) {
  __shared__ unsigned short Al[2][BM * 64];   // 32 KB
  __shared__ unsigned short Bgl[2][64 * 64];  // 16 KB
  __shared__ unsigned short Bul[2][64 * 64];  // 16 KB
  int flat = blockIdx.x + blockIdx.y * MT_MAX;      // grid (136,43), 5848 = 8*731
  int swz = (flat & 7) * 731 + (flat >> 3);         // XCD-chunked, m-fastest
  int mt = swz % MT_MAX;
  int nb = swz / MT_MAX;
  if (mt >= tpfx[EE]) return;
  int e = 0;
  while (mt >= tpfx[e + 1]) ++e;
  int n0 = nb << 6;
  size_t row0 = (size_t)mt << 7;
  const unsigned short* wge = wgT + (size_t)e * DD * HH;
  const unsigned short* wue = wuT + (size_t)e * DD * HH;
  int tid = threadIdx.x, wv = tid >> 6, lane = tid & 63;
  int wm = wv >> 1, wn = wv & 1;

  f32x4 zf = {0.f, 0.f, 0.f, 0.f};
  f32x4 ag[4][2], au[4][2];
#pragma unroll
  for (int i = 0; i < 4; ++i)
#pragma unroll
    for (int j = 0; j < 2; ++j) { ag[i][j] = zf; au[i][j] = zf; }

  // persistent staging pointers (bumped +64 elems per stage call; 8 loads/stage)
  const unsigned short* srcA0;
  const unsigned short* srcA1;
  const unsigned short* srcA2;
  const unsigned short* srcA3;
  unsigned short* dstA0; unsigned short* dstA1;
  unsigned short* dstA2; unsigned short* dstA3;
  {
#pragma unroll
    for (int i = 0; i < 4; ++i) {
      int g = (wv << 2) + i;
      int p = (g << 6) + lane;
      int r = p >> 3, c = (p & 7) ^ (r & 7);
      const unsigned short* s = Xg + (row0 + r) * DD + (size_t)(c << 3);
      unsigned short* d = &Al[0][(size_t)g << 9];
      if (i == 0) { srcA0 = s; dstA0 = d; }
      else if (i == 1) { srcA1 = s; dstA1 = d; }
      else if (i == 2) { srcA2 = s; dstA2 = d; }
      else { srcA3 = s; dstA3 = d; }
    }
  }
  const unsigned short* srcG0; const unsigned short* srcG1;
  const unsigned short* srcU0; const unsigned short* srcU1;
  unsigned short* dstG0; unsigned short* dstG1;
  unsigned short* dstU0; unsigned short* dstU1;
  {
#pragma unroll
    for (int i = 0; i < 2; ++i) {
      int g = (wv << 1) + i;
      int p = (g << 6) + lane;
      int n = p >> 3, c = (p & 7) ^ (n & 7);
      const unsigned short* sg = wge + (size_t)(n0 + n) * DD + (size_t)(c << 3);
      const unsigned short* su = wue + (size_t)(n0 + n) * DD + (size_t)(c << 3);
      unsigned short* dg = &Bgl[0][(size_t)g << 9];
      unsigned short* du = &Bul[0][(size_t)g << 9];
      if (i == 0) { srcG0 = sg; srcU0 = su; dstG0 = dg; dstU0 = du; }
      else { srcG1 = sg; srcU1 = su; dstG1 = dg; dstU1 = du; }
    }
  }

  auto stage = [&](int cur) {
    int ao = cur << 13;   // elements: Al buffer = 8192
    int bo = cur << 12;   // elements: Bgl/Bul buffer = 4096
    gload_lds16(srcA0, dstA0 + ao); srcA0 += 64;
    gload_lds16(srcA1, dstA1 + ao); srcA1 += 64;
    gload_lds16(srcA2, dstA2 + ao); srcA2 += 64;
    gload_lds16(srcA3, dstA3 + ao); srcA3 += 64;
    gload_lds16(srcG0, dstG0 + bo); srcG0 += 64;
    gload_lds16(srcU0, dstU0 + bo); srcU0 += 64;
    gload_lds16(srcG1, dstG1 + bo); srcG1 += 64;
    gload_lds16(srcU1, dstU1 + bo); srcU1 += 64;
  };

  auto mma = [&](int cur) {
    const unsigned short* al  = &Al[0][0]  + (cur << 13);
    const unsigned short* bgl = &Bgl[0][0] + (cur << 12);
    const unsigned short* bul = &Bul[0][0] + (cur << 12);
#pragma unroll
    for (int ks = 0; ks < 2; ++ks) {
      int cch = (ks << 2) + (lane >> 4);
      s16x8 af[4];
#pragma unroll
      for (int fm = 0; fm < 4; ++fm) {
        int r = (wm << 6) + (fm << 4) + (lane & 15);
        af[fm] = *(const s16x8*)(al + (r << 6) + ((cch ^ (r & 7)) << 3));
      }
      s16x8 bg[2], bu[2];
#pragma unroll
      for (int fn = 0; fn < 2; ++fn) {
        int n = (wn << 5) + (fn << 4) + (lane & 15);
        int o = (n << 6) + ((cch ^ (n & 7)) << 3);
        bg[fn] = *(const s16x8*)(bgl + o);
        bu[fn] = *(const s16x8*)(bul + o);
      }
#pragma unroll
      for (int fm = 0; fm < 4; ++fm)
#pragma unroll
        for (int fn = 0; fn < 2; ++fn) {
          ag[fm][fn] = __builtin_amdgcn_mfma_f32_16x16x32_bf16(af[fm], bg[fn], ag[fm][fn], 0, 0, 0);
          au[fm][fn] = __builtin_amdgcn_mfma_f32_16x16x32_bf16(af[fm], bu[fn], au[fm][fn], 0, 0, 0);
        }
    }
  };

  const int NT = DD / 64;   // 16
  stage(0);
  stage(1);                 // 16 loads in flight
  for (int kt = 0; kt < NT - 1; ++kt) {
    int cur = kt & 1;
    asm volatile("s_waitcnt vmcnt(8)" ::: "memory");   // oldest 8 (buf[cur]) done
    __builtin_amdgcn_s_barrier();
    __builtin_amdgcn_sched_barrier(0);
    mma(cur);
    __builtin_amdgcn_sched_barrier(0);
    __builtin_amdgcn_s_barrier();                      // all readers of buf[cur] done
    if (kt < NT - 2) stage(cur);                       // refill freed buffer (kt+2)
  }
  {
    int cur = (NT - 1) & 1;
    asm volatile("s_waitcnt vmcnt(0)" ::: "memory");
    __builtin_amdgcn_s_barrier();
    __builtin_amdgcn_sched_barrier(0);
    mma(cur);
  }

#pragma unroll
  for (int fm = 0; fm < 4; ++fm)
#pragma unroll
    for (int fn = 0; fn < 2; ++fn)
#pragma unroll
      for (int j = 0; j < 4; ++j) {
        float gv = ag[fm][fn][j];
        float uv = au[fm][fn][j];
        float hv = gv / (1.f + __expf(-gv)) * uv;
        int r = (wm << 6) + (fm << 4) + ((lane >> 4) << 2) + j;
        int cc = (wn << 5) + (fn << 4) + (lane & 15);
        hbuf[(row0 + r) * HH + (size_t)(n0 + cc)] = (unsigned short)f2bf1(hv);
      }
}

// ---------------- FC2: depth-2 pipeline, counted vmcnt(8), raw barriers ----------------
// tile 128(M) x 128(N) x 64(K); 4 waves (2x2); wave 64x64
__global__ __launch_bounds__(256) void k_fc2t(
    const unsigned short* __restrict__ hbuf, const unsigned short* __restrict__ wdT,
    const int* __restrict__ cnt, const int* __restrict__ tpfx,
    const int* __restrict__ tok, const float* __restrict__ wgt,
    float* __restrict__ out) {
  __shared__ unsigned short Al[2][BM * 64];    // 32 KB
  __shared__ unsigned short Bl[2][128 * 64];   // 32 KB
  int flat = blockIdx.x + blockIdx.y * MT_MAX;      // grid (136,8), 1088 = 8*136
  int swz = (flat & 7) * MT_MAX + (flat >> 3);
  int mt = swz % MT_MAX;
  int nb = swz / MT_MAX;
  if (mt >= tpfx[EE]) return;
  int e = 0;
  while (mt >= tpfx[e + 1]) ++e;
  int n0 = nb << 7;
  size_t row0 = (size_t)mt << 7;
  int mrem = cnt[e] - ((mt - tpfx[e]) << 7);
  if (mrem > 128) mrem = 128;
  const unsigned short* wde = wdT + (size_t)e * DD * HH;  // [1024][2752]
  int tid = threadIdx.x, wv = tid >> 6, lane = tid & 63;
  int wm = wv >> 1, wn = wv & 1;

  f32x4 zf = {0.f, 0.f, 0.f, 0.f};
  f32x4 acc[4][4];
#pragma unroll
  for (int i = 0; i < 4; ++i)
#pragma unroll
    for (int j = 0; j < 4; ++j) acc[i][j] = zf;

  const unsigned short* srcA0; const unsigned short* srcA1;
  const unsigned short* srcA2; const unsigned short* srcA3;
  const unsigned short* srcB0; const unsigned short* srcB1;
  const unsigned short* srcB2; const unsigned short* srcB3;
  unsigned short* dstA0; unsigned short* dstA1;
  unsigned short* dstA2; unsigned short* dstA3;
  unsigned short* dstB0; unsigned short* dstB1;
  unsigned short* dstB2; unsigned short* dstB3;
  {
#pragma unroll
    for (int i = 0; i < 4; ++i) {
      int g = (wv << 2) + i;
      int p = (g << 6) + lane;
      int r = p >> 3, c = (p & 7) ^ (r & 7);
      const unsigned short* sa = hbuf + (row0 + r) * HH + (size_t)(c << 3);
      const unsigned short* sb = wde + (size_t)(n0 + r) * HH + (size_t)(c << 3);
      unsigned short* da = &Al[0][(size_t)g << 9];
      unsigned short* db = &Bl[0][(size_t)g << 9];
      if (i == 0) { srcA0 = sa; srcB0 = sb; dstA0 = da; dstB0 = db; }
      else if (i == 1) { srcA1 = sa; srcB1 = sb; dstA1 = da; dstB1 = db; }
      else if (i == 2) { srcA2 = sa; srcB2 = sb; dstA2 = da; dstB2 = db; }
      else { srcA3 = sa; srcB3 = sb; dstA3 = da; dstB3 = db; }
    }
  }

  auto stage = [&](int cur) {
    int o = cur << 13;   // both buffers are 8192 elements
    gload_lds16(srcA0, dstA0 + o); srcA0 += 64;
    gload_lds16(srcB0, dstB0 + o); srcB0 += 64;
    gload_lds16(srcA1, dstA1 + o); srcA1 += 64;
    gload_lds16(srcB1, dstB1 + o); srcB1 += 64;
    gload_lds16(srcA2, dstA2 + o); srcA2 += 64;
    gload_lds16(srcB2, dstB2 + o); srcB2 += 64;
    gload_lds16(srcA3, dstA3 + o); srcA3 += 64;
    gload_lds16(srcB3, dstB3 + o); srcB3 += 64;
  };

  auto mma = [&](int cur) {
    const unsigned short* al = &Al[0][0] + (cur << 13);
    const unsigned short* bl = &Bl[0][0] + (cur << 13);
#pragma unroll
    for (int ks = 0; ks < 2; ++ks) {
      int cch = (ks << 2) + (lane >> 4);
      s16x8 af[4], bf[4];
#pragma unroll
      for (int fm = 0; fm < 4; ++fm) {
        int r = (wm << 6) + (fm << 4) + (lane & 15);
        af[fm] = *(const s16x8*)(al + (r << 6) + ((cch ^ (r & 7)) << 3));
      }
#pragma unroll
      for (int fn = 0; fn < 4; ++fn) {
        int n = (wn << 6) + (fn << 4) + (lane & 15);
        bf[fn] = *(const s16x8*)(bl + (n << 6) + ((cch ^ (n & 7)) << 3));
      }
#pragma unroll
      for (int fm = 0; fm < 4; ++fm)
#pragma unroll
        for (int fn = 0; fn < 4; ++fn)
          acc[fm][fn] = __builtin_amdgcn_mfma_f32_16x16x32_bf16(af[fm], bf[fn], acc[fm][fn], 0, 0, 0);
    }
  };

  const int NT = HH / 64;   // 43
  stage(0);
  stage(1);
  for (int kt = 0; kt < NT - 1; ++kt) {
    int cur = kt & 1;
    asm volatile("s_waitcnt vmcnt(8)" ::: "memory");
    __builtin_amdgcn_s_barrier();
    __builtin_amdgcn_sched_barrier(0);
    mma(cur);
    __builtin_amdgcn_sched_barrier(0);
    __builtin_amdgcn_s_barrier();
    if (kt < NT - 2) stage(cur);
  }
  {
    int cur = (NT - 1) & 1;
    asm volatile("s_waitcnt vmcnt(0)" ::: "memory");
    __builtin_amdgcn_s_barrier();
    __builtin_amdgcn_sched_barrier(0);
    mma(cur);
  }

#pragma unroll
  for (int fm = 0; fm < 4; ++fm)
#pragma unroll
    for (int j = 0; j < 4; ++j) {
      int r = (wm << 6) + (fm << 4) + ((lane >> 4) << 2) + j;
      if (r < mrem) {
        int tk = tok[row0 + r];
        float cw = wgt[row0 + r];
        float* ob = out + (size_t)tk * DD + (size_t)(n0 + (wn << 6) + (lane & 15));
#pragma unroll
        for (int fn = 0; fn < 4; ++fn)
          atomicAdd(ob + (fn << 4), acc[fm][fn][j] * cw);
      }
    }
}

// ================= fallback (round-2) kernels: in-loop fp32->bf16 convert =================
__global__ __launch_bounds__(256) void k_fc1_cv(
    const unsigned short* __restrict__ Xg, const float* __restrict__ wg,
    const float* __restrict__ wu, const int* __restrict__ tpfx,
    unsigned short* __restrict__ hbuf) {
  __shared__ unsigned short Al[BM * 64];
  __shared__ unsigned short Bgl[64 * 64];
  __shared__ unsigned short Bul[64 * 64];
  int mt = blockIdx.x;
  if (mt >= tpfx[EE]) return;
  int e = 0;
  while (mt >= tpfx[e + 1]) ++e;
  int n0 = blockIdx.y << 6;
  size_t row0 = (size_t)mt << 7;
  const float* wge = wg + (size_t)e * DD * HH;
  const float* wue = wu + (size_t)e * DD * HH;
  int tid = threadIdx.x, wv = tid >> 6, lane = tid & 63;
  int wm = wv >> 1, wn = wv & 1;
  f32x4 zf = {0.f, 0.f, 0.f, 0.f};
  f32x4 ag[4][2], au[4][2];
#pragma unroll
  for (int i = 0; i < 4; ++i)
#pragma unroll
    for (int j = 0; j < 2; ++j) { ag[i][j] = zf; au[i][j] = zf; }
  for (int kt = 0; kt < DD / 64; ++kt) {
    int k0 = kt << 6;
#pragma unroll
    for (int i = 0; i < 4; ++i) {
      int g = (wv << 2) + i;
      int p = (g << 6) + lane;
      int r = p >> 3, c = (p & 7) ^ (r & 7);
      gload_lds16(Xg + (row0 + r) * DD + (size_t)(k0 + (c << 3)), Al + ((size_t)g << 9));
    }
#pragma unroll
    for (int a2 = 0; a2 < 2; ++a2) {
      int idx = tid + (a2 << 8);
      int kk = (idx >> 4) << 1;
      int nn = (idx & 15) << 2;
      const float* pg = wge + (size_t)(k0 + kk) * HH + (n0 + nn);
      const float* pu = wue + (size_t)(k0 + kk) * HH + (n0 + nn);
      float4 g0 = *(const float4*)pg;
      float4 g1 = *(const float4*)(pg + HH);
      float4 u0 = *(const float4*)pu;
      float4 u1 = *(const float4*)(pu + HH);
      const float* g0f = (const float*)&g0; const float* g1f = (const float*)&g1;
      const float* u0f = (const float*)&u0; const float* u1f = (const float*)&u1;
      int kb = kk << 1, ch = kb >> 4, inb = kb & 15;
#pragma unroll
      for (int j = 0; j < 4; ++j) {
        int n = nn + j;
        int off = (n << 7) + ((ch ^ bswz(n)) << 4) + inb;
        *(unsigned int*)((char*)Bgl + off) = f2bf2(g0f[j], g1f[j]);
        *(unsigned int*)((char*)Bul + off) = f2bf2(u0f[j], u1f[j]);
      }
    }
    __syncthreads();
#pragma unroll
    for (int ks = 0; ks < 2; ++ks) {
      int cch = (ks << 2) + (lane >> 4);
      s16x8 af[4];
#pragma unroll
      for (int fm = 0; fm < 4; ++fm) {
        int r = (wm << 6) + (fm << 4) + (lane & 15);
        af[fm] = *(const s16x8*)(Al + (r << 6) + ((cch ^ (r & 7)) << 3));
      }
      s16x8 bg[2], bu[2];
#pragma unroll
      for (int fn = 0; fn < 2; ++fn) {
        int n = (wn << 5) + (fn << 4) + (lane & 15);
        int o = (n << 6) + ((cch ^ bswz(n)) << 3);
        bg[fn] = *(const s16x8*)(Bgl + o);
        bu[fn] = *(const s16x8*)(Bul + o);
      }
#pragma unroll
      for (int fm = 0; fm < 4; ++fm)
#pragma unroll
        for (int fn = 0; fn < 2; ++fn) {
          ag[fm][fn] = __builtin_amdgcn_mfma_f32_16x16x32_bf16(af[fm], bg[fn], ag[fm][fn], 0, 0, 0);
          au[fm][fn] = __builtin_amdgcn_mfma_f32_16x16x32_bf16(af[fm], bu[fn], au[fm][fn], 0, 0, 0);
        }
    }
    __syncthreads();
  }
#pragma unroll
  for (int fm = 0; fm < 4; ++fm)
#pragma unroll
    for (int fn = 0; fn < 2; ++fn)
#pragma unroll
      for (int j = 0; j < 4; ++j) {
        float gv = ag[fm][fn][j];
        float uv = au[fm][fn][j];
        float hv = gv / (1.f + __expf(-gv)) * uv;
        int r = (wm << 6) + (fm << 4) + ((lane >> 4) << 2) + j;
        int cc = (wn << 5) + (fn << 4) + (lane & 15);
        hbuf[(row0 + r) * HH + (size_t)(n0 + cc)] = (unsigned short)f2bf1(hv);
      }
}

__global__ __launch_bounds__(256) void k_fc2_cv(
    const unsigned short* __restrict__ hbuf, const float* __restrict__ wd,
    const int* __restrict__ cnt, const int* __restrict__ tpfx,
    const int* __restrict__ tok, const float* __restrict__ wgt,
    float* __restrict__ out) {
  __shared__ unsigned short Al[BM * 64];
  __shared__ unsigned short Bl[128 * 64];
  int mt = blockIdx.x;
  if (mt >= tpfx[EE]) return;
  int e = 0;
  while (mt >= tpfx[e + 1]) ++e;
  int n0 = blockIdx.y << 7;
  size_t row0 = (size_t)mt << 7;
  int mrem = cnt[e] - ((mt - tpfx[e]) << 7);
  if (mrem > 128) mrem = 128;
  const float* wde = wd + (size_t)e * HH * DD;
  int tid = threadIdx.x, wv = tid >> 6, lane = tid & 63;
  int wm = wv >> 1, wn = wv & 1;
  f32x4 zf = {0.f, 0.f, 0.f, 0.f};
  f32x4 acc[4][4];
#pragma unroll
  for (int i = 0; i < 4; ++i)
#pragma unroll
    for (int j = 0; j < 4; ++j) acc[i][j] = zf;
  for (int kt = 0; kt < HH / 64; ++kt) {
    int k0 = kt << 6;
#pragma unroll
    for (int i = 0; i < 4; ++i) {
      int g = (wv << 2) + i;
      int p = (g << 6) + lane;
      int r = p >> 3, c = (p & 7) ^ (r & 7);
      gload_lds16(hbuf + (row0 + r) * HH + (size_t)(k0 + (c << 3)), Al + ((size_t)g << 9));
    }
#pragma unroll
    for (int a2 = 0; a2 < 4; ++a2) {
      int idx = tid + (a2 << 8);
      int kk = (idx >> 5) << 1;
      int nn = (idx & 31) << 2;
      const float* pb = wde + (size_t)(k0 + kk) * DD + (n0 + nn);
      float4 b0 = *(const float4*)pb;
      float4 b1 = *(const float4*)(pb + DD);
      const float* b0f = (const float*)&b0;
      const float* b1f = (const float*)&b1;
      int kb = kk << 1, ch = kb >> 4, inb = kb & 15;
#pragma unroll
      for (int j = 0; j < 4; ++j) {
        int n = nn + j;
        int off = (n << 7) + ((ch ^ bswz(n)) << 4) + inb;
        *(unsigned int*)((char*)Bl + off) = f2bf2(b0f[j], b1f[j]);
      }
    }
    __syncthreads();
#pragma unroll
    for (int ks = 0; ks < 2; ++ks) {
      int cch = (ks << 2) + (lane >> 4);
      s16x8 af[4], bf[4];
#pragma unroll
      for (int fm = 0; fm < 4; ++fm) {
        int r = (wm << 6) + (fm << 4) + (lane & 15);
        af[fm] = *(const s16x8*)(Al + (r << 6) + ((cch ^ (r & 7)) << 3));
      }
#pragma unroll
      for (int fn = 0; fn < 4; ++fn) {
        int n = (wn << 6) + (fn << 4) + (lane & 15);
        bf[fn] = *(const s16x8*)(Bl + (n << 6) + ((cch ^ bswz(n)) << 3));
      }
#pragma unroll
      for (int fm = 0; fm < 4; ++fm)
#pragma unroll
        for (int fn = 0; fn < 4; ++fn)
          acc[fm][fn] = __builtin_amdgcn_mfma_f32_16x16x32_bf16(af[fm], bf[fn], acc[fm][fn], 0, 0, 0);
    }
    __syncthreads();
  }
#pragma unroll
  for (int fm = 0; fm < 4; ++fm)
#pragma unroll
    for (int j = 0; j < 4; ++j) {
      int r = (wm << 6) + (fm << 4) + ((lane >> 4) << 2) + j;
      if (r < mrem) {
        int tk = tok[row0 + r];
        float cw = wgt[row0 + r];
        float* ob = out + (size_t)tk * DD + (size_t)(n0 + (wn << 6) + (lane & 15));
#pragma unroll
        for (int fn = 0; fn < 4; ++fn)
          atomicAdd(ob + (fn << 4), acc[fm][fn][j] * cw);
      }
    }
}

extern "C" void kernel_launch(void* const* d_in, const int* in_sizes, int n_in,
                              void* d_out, int out_size, void* d_ws, size_t ws_size,
                              hipStream_t stream) {
  const float* x  = (const float*)d_in[0];
  const float* rw = (const float*)d_in[1];
  const float* wg = (const float*)d_in[2];
  const float* wu = (const float*)d_in[3];
  const float* wd = (const float*)d_in[4];
  float* out = (float*)d_out;

  // workspace layout
  char* w = (char*)d_ws;
  int* cnt    = (int*)(w + 0);
  int* cursor = (int*)(w + 32);
  int* tpfx   = (int*)(w + 64);
  int* topi   = (int*)(w + 256);
  float* topw = (float*)(w + 65792);
  int* tok    = (int*)(w + 131328);
  float* wgt  = (float*)(w + 200960);
  unsigned short* Xg  = (unsigned short*)(w + 270592);       // 35,651,584 B
  unsigned short* hb  = (unsigned short*)(w + 35922176ULL);  // 95,813,632 B
  unsigned short* wgT = (unsigned short*)(w + 131735808ULL); // 45,088,768 B
  unsigned short* wuT = (unsigned short*)(w + 176824576ULL); // 45,088,768 B
  unsigned short* wdT = wgT;  // reuses wgT slot AFTER fc1
  const size_t NEED = 221913344ULL;

  hipMemsetAsync(d_out, 0, (size_t)T_TOKENS * DD * sizeof(float), stream);
  k_init<<<1, 64, 0, stream>>>(cursor);
  k_router<<<T_TOKENS / 4, 256, 0, stream>>>(x, rw, topi, topw);
  k_assign<<<T_TOKENS / 256, 256, 0, stream>>>(topi, cursor);
  k_offsets<<<1, 64, 0, stream>>>(cursor, cnt, tpfx);
  k_copy<<<T_TOKENS / 4, 256, 0, stream>>>(x, topi, topw, tpfx, tok, wgt, Xg);
  k_padzero<<<256, 256, 0, stream>>>(cnt, tpfx, Xg);

  if (ws_size >= NEED) {
    k_wtrans<<<EE * 16 * 43, 256, 0, stream>>>(wg, wgT, DD, HH);
    k_wtrans<<<EE * 16 * 43, 256, 0, stream>>>(wu, wuT, DD, HH);
    k_fc1t<<<dim3(MT_MAX, HH / 64), 256, 0, stream>>>(Xg, wgT, wuT, tpfx, hb);
    k_wtrans<<<EE * 43 * 16, 256, 0, stream>>>(wd, wdT, HH, DD);  // over wgT slot
    k_fc2t<<<dim3(MT_MAX, DD / 128), 256, 0, stream>>>(hb, wdT, cnt, tpfx, tok, wgt, out);
  } else {
    k_fc1_cv<<<dim3(MT_MAX, HH / 64), 256, 0, stream>>>(Xg, wg, wu, tpfx, hb);
    k_fc2_cv<<<dim3(MT_MAX, DD / 128), 256, 0, stream>>>(hb, wd, cnt, tpfx, tok, wgt, out);
  }
}